// Round 11
// baseline (506.948 us; speedup 1.0000x reference)
//
#include <hip/hip_runtime.h>
#include <hip/hip_fp16.h>
#include <math.h>

#define BB 4
#define NN 2304
#define CC 256
#define HS 48
#define HID 1024
#define BNROWS (BB * NN)                 // 9216
#define ATTN_SCALE 0.17677669529663687f  // 32^-0.5

typedef _Float16 f16;
typedef __attribute__((ext_vector_type(2))) _Float16 h2;
typedef __attribute__((ext_vector_type(8))) _Float16 h8;
typedef __attribute__((ext_vector_type(4))) float f4;

#define GLLS16(g, l)                                                        \
    __builtin_amdgcn_global_load_lds(                                       \
        (const __attribute__((address_space(1))) unsigned int*)(g),         \
        (__attribute__((address_space(3))) unsigned int*)(l), 16, 0, 0)
// global_load_lds -> ds_read dependency is untracked by the compiler;
// explicit waits with memory clobber pin the ordering.
#define WAIT_VM0()   asm volatile("s_waitcnt vmcnt(0)" ::: "memory")
#define WAIT_VM2()   asm volatile("s_waitcnt vmcnt(2)" ::: "memory")
#define WAIT_VM4()   asm volatile("s_waitcnt vmcnt(4)" ::: "memory")
#define WAIT_VM5()   asm volatile("s_waitcnt vmcnt(5)" ::: "memory")
#define WAIT_VM6()   asm volatile("s_waitcnt vmcnt(6)" ::: "memory")
#define WAIT_LGKM0() asm volatile("s_waitcnt lgkmcnt(0)" ::: "memory")

static __device__ __forceinline__ float wave_sum64(float v) {
    v += __shfl_xor(v, 32, 64);
    v += __shfl_xor(v, 16, 64);
    v += __shfl_xor(v, 8, 64);
    v += __shfl_xor(v, 4, 64);
    v += __shfl_xor(v, 2, 64);
    v += __shfl_xor(v, 1, 64);
    return v;
}

// bijective XCD swizzle: cluster consecutive linear block ids onto one XCD so
// blocks sharing a B-panel hit the same per-XCD L2. Requires nwg % 8 == 0.
static __device__ __forceinline__ int xcd_swizzle_lin() {
    const int gx = (int)gridDim.x;
    const int lin = (int)blockIdx.y * gx + (int)blockIdx.x;
    const int nwg = gx * (int)gridDim.y;
    return (nwg & 7) ? lin : ((lin & 7) * (nwg >> 3) + (lin >> 3));
}

// software grid barrier: device-scope atomics are coherent across XCDs.
// Requires all blocks co-resident (LDS 48.5KB -> 3/CU cap; 512 blocks = 2/CU).
// threadfence release publishes this block's stores (L2 writeback); acquire
// after the spin invalidates before consuming other blocks' data.
static __device__ __forceinline__ void sw_gbar(unsigned* ctr, unsigned target) {
    __threadfence();
    __syncthreads();
    if (threadIdx.x == 0) {
        __hip_atomic_fetch_add(ctr, 1u, __ATOMIC_ACQ_REL,
                               __HIP_MEMORY_SCOPE_AGENT);
        unsigned v;
        do {
            __builtin_amdgcn_s_sleep(2);
            v = __hip_atomic_load(ctr, __ATOMIC_ACQUIRE,
                                  __HIP_MEMORY_SCOPE_AGENT);
        } while (v < target);
    }
    __syncthreads();
    __threadfence();
}

// ---------------- merged prep + LN1 ----------------
__global__ __launch_bounds__(256) void prep_ln1_kernel(
    const float* __restrict__ x, const float* __restrict__ xkv,
    const float* __restrict__ Wq, const float* __restrict__ Wk,
    const float* __restrict__ Wv, const float* __restrict__ Wp,
    const float* __restrict__ W1, const float* __restrict__ W2,
    const float* __restrict__ bq, const float* __restrict__ bk,
    const float* __restrict__ bv,
    const float* __restrict__ g, const float* __restrict__ be,
    f16* __restrict__ WqkvT, f16* __restrict__ WpT,
    f16* __restrict__ W1T, f16* __restrict__ W2T, float* __restrict__ bqkv,
    f16* __restrict__ hq, f16* __restrict__ hkv, unsigned* gctr)
{
    __shared__ float tt[32][33];
    int bx = blockIdx.x;
    const int tid = threadIdx.x;
    if (bx < 768) {
        const float* src; f16* dst; int K, N;
        if (bx < 64)        { src = Wq; dst = WqkvT;           K = 256;  N = 256; }
        else if (bx < 128)  { src = Wk; dst = WqkvT + 65536;   K = 256;  N = 256;  bx -= 64; }
        else if (bx < 192)  { src = Wv; dst = WqkvT + 131072;  K = 256;  N = 256;  bx -= 128; }
        else if (bx < 256)  { src = Wp; dst = WpT;             K = 256;  N = 256;  bx -= 192; }
        else if (bx < 512)  { src = W1; dst = W1T;             K = 256;  N = 1024; bx -= 256; }
        else                { src = W2; dst = W2T;             K = 1024; N = 256;  bx -= 512; }
        const int tN = N >> 5;
        const int kt = bx / tN, nt = bx - kt * tN;
        const int rr = tid >> 5, cc = tid & 31;
#pragma unroll
        for (int j = 0; j < 4; ++j)
            tt[rr + 8 * j][cc] = src[(size_t)(kt * 32 + rr + 8 * j) * N + nt * 32 + cc];
        __syncthreads();
#pragma unroll
        for (int j = 0; j < 4; ++j)
            dst[(size_t)(nt * 32 + rr + 8 * j) * K + kt * 32 + cc] = (f16)tt[cc][rr + 8 * j];
        return;
    }
    if (bx == 768) {
        if (tid < 256) {
            bqkv[tid]       = bq[tid];
            bqkv[tid + 256] = bk[tid];
            bqkv[tid + 512] = bv[tid];
        }
        if (gctr && tid < 8)
            __hip_atomic_store(&gctr[tid], 0u, __ATOMIC_RELEASE,
                               __HIP_MEMORY_SCOPE_AGENT);
        return;
    }
    // LN1
    const int r = (bx - 769) * 4 + (tid >> 6);  // 0..2*BNROWS-1
    const int lane = tid & 63;
    const float* src; f16* dst;
    if (r < BNROWS) { src = x + (size_t)r * CC;              dst = hq + (size_t)r * CC; }
    else { src = xkv + (size_t)(r - BNROWS) * CC; dst = hkv + (size_t)(r - BNROWS) * CC; }
    const float4 v = ((const float4*)src)[lane];
    const float mu = wave_sum64(v.x + v.y + v.z + v.w) * (1.0f / CC);
    const float d0 = v.x - mu, d1 = v.y - mu, d2 = v.z - mu, d3 = v.w - mu;
    const float var = wave_sum64(d0 * d0 + d1 * d1 + d2 * d2 + d3 * d3) * (1.0f / CC);
    const float rs = rsqrtf(var + 1e-6f);
    const float4 g4 = ((const float4*)g)[lane];
    const float4 b4 = ((const float4*)be)[lane];
    h2 o01 = (h2){(f16)(d0 * rs * g4.x + b4.x), (f16)(d1 * rs * g4.y + b4.y)};
    h2 o23 = (h2){(f16)(d2 * rs * g4.z + b4.z), (f16)(d3 * rs * g4.w + b4.w)};
    ((h2*)dst)[lane * 2] = o01;
    ((h2*)dst)[lane * 2 + 1] = o23;
}

// ---------------- wave-autonomous MFMA GEMM, double-buffered (QKV) --------
// Exact r5 structure (best measured). Wave owns 32(M)x64(N); two private
// 6 KB buffers; vmcnt(6) drains only the 6 oldest loads.
template <bool QKV>
__global__ __launch_bounds__(256, 4) void gemm_wave(
    const f16* __restrict__ Aq, const f16* __restrict__ Akv,
    const f16* __restrict__ Bt, const float* __restrict__ bias,
    void* __restrict__ out1, void* __restrict__ outkv, int N, int K)
{
    __shared__ f16 lds[4 * 6144];   // 4 waves x 2 buffers x 3072 f16 = 48 KB
    const int tid = threadIdx.x;
    const int wid = tid >> 6, lane = tid & 63;
    const int ln15 = lane & 15, quad = lane >> 4;
    const int jr = lane >> 2, js = lane & 3;
    f16* slot = lds + wid * 6144;
    const int sl = xcd_swizzle_lin();
    const int gx = (int)gridDim.x;
    const int bx = sl % gx, by = sl / gx;
    const int n0 = bx * 64;
    const int m0 = (by * 4 + wid) * 32;
    const f16* Ap = QKV ? (n0 < 256 ? Aq : Akv) : Aq;

    size_t ga[2], gb[4];
#pragma unroll
    for (int i = 0; i < 2; ++i) {
        const int r = i * 16 + jr;
        const int q = (js - (r >> 1)) & 3;
        ga[i] = (size_t)(m0 + r) * K + q * 8;
    }
#pragma unroll
    for (int i = 0; i < 4; ++i) {
        const int r = i * 16 + jr;
        const int q = (js - (r >> 1)) & 3;
        gb[i] = (size_t)(n0 + r) * K + q * 8;
    }
    int aoff[2], boff[4];
#pragma unroll
    for (int mt = 0; mt < 2; ++mt) {
        const int r = mt * 16 + ln15;
        aoff[mt] = (r * 4 + ((quad + (r >> 1)) & 3)) * 16;
    }
#pragma unroll
    for (int nt = 0; nt < 4; ++nt) {
        const int r = nt * 16 + ln15;
        boff[nt] = (r * 4 + ((quad + (r >> 1)) & 3)) * 16;
    }

    f4 acc[2][4];
#pragma unroll
    for (int i = 0; i < 2; ++i)
#pragma unroll
        for (int j = 0; j < 4; ++j) acc[i][j] = (f4){0.f, 0.f, 0.f, 0.f};

    {
        f16* Al = slot;
        f16* Bl = slot + 1024;
#pragma unroll
        for (int i = 0; i < 2; ++i) GLLS16(Ap + ga[i], Al + i * 512);
#pragma unroll
        for (int i = 0; i < 4; ++i) GLLS16(Bt + gb[i], Bl + i * 512);
    }

    int cur = 0;
    for (int k0 = 0; k0 < K; k0 += 32) {
        const bool more = (k0 + 32 < K);
        f16* Ac = slot + cur * 3072;
        f16* Bc = Ac + 1024;
        if (more) {
            f16* An = slot + (cur ^ 1) * 3072;
            f16* Bn = An + 1024;
            WAIT_LGKM0();
#pragma unroll
            for (int i = 0; i < 2; ++i) GLLS16(Ap + ga[i] + k0 + 32, An + i * 512);
#pragma unroll
            for (int i = 0; i < 4; ++i) GLLS16(Bt + gb[i] + k0 + 32, Bn + i * 512);
            WAIT_VM6();
        } else {
            WAIT_VM0();
        }
        h8 aF[2], bF[4];
#pragma unroll
        for (int nt = 0; nt < 4; ++nt)
            bF[nt] = *(const h8*)((const char*)Bc + boff[nt]);
#pragma unroll
        for (int mt = 0; mt < 2; ++mt)
            aF[mt] = *(const h8*)((const char*)Ac + aoff[mt]);
#pragma unroll
        for (int mt = 0; mt < 2; ++mt)
#pragma unroll
            for (int nt = 0; nt < 4; ++nt)
                acc[mt][nt] = __builtin_amdgcn_mfma_f32_16x16x32_f16(
                    aF[mt], bF[nt], acc[mt][nt], 0, 0, 0);
        cur ^= 1;
    }

    // epilogue; for QKV the 64-col block never straddles the Q|KV split.
    f16* qdst = nullptr; int qstr = 0, qn0 = 0;
    if (QKV) {
        if (n0 < 256) { qdst = (f16*)out1;  qstr = 256; qn0 = n0; }
        else          { qdst = (f16*)outkv; qstr = 512; qn0 = n0 - 256; }
    }
#pragma unroll
    for (int nt = 0; nt < 4; ++nt) {
        const int gn = n0 + nt * 16 + ln15;
        const float bs = bias[gn];
#pragma unroll
        for (int mt = 0; mt < 2; ++mt) {
#pragma unroll
            for (int r = 0; r < 4; ++r) {
                const int gm = m0 + mt * 16 + quad * 4 + r;
                float v = acc[mt][nt][r] + bs;
                if (QKV) {
                    qdst[(size_t)gm * qstr + qn0 + nt * 16 + ln15] = (f16)v;
                } else {
                    ((f16*)out1)[(size_t)gm * N + gn] = (f16)v;
                }
            }
        }
    }
}

// ------------- out-proj + residual + LN2 body (16-row job) -------------
// Exact r9 gemm_op_ln2 body, parameterized by job row-group and LDS base.
static __device__ __forceinline__ void opln2_body(
    const f16* __restrict__ Aa, const f16* __restrict__ Bt,
    const float* __restrict__ bias, const float* __restrict__ xres,
    const float* __restrict__ g, const float* __restrict__ be,
    f16* __restrict__ x1, f16* __restrict__ m2, int m0, f16* ldsb,
    float (*sred)[4][2])
{
    const int tid = threadIdx.x;
    const int wid = tid >> 6, lane = tid & 63;
    const int ln15 = lane & 15, quad = lane >> 4;
    const int jr = lane >> 2, js = lane & 3;
    f16* slot = ldsb + wid * 5120;
    const int n0 = wid * 64;
    const int K = 256;

    size_t ga, gb[4];
    {
        const int q = (js - (jr >> 1)) & 3;
        ga = (size_t)(m0 + jr) * K + q * 8;
    }
#pragma unroll
    for (int i = 0; i < 4; ++i) {
        const int r = i * 16 + jr;
        const int q = (js - (r >> 1)) & 3;
        gb[i] = (size_t)(n0 + r) * K + q * 8;
    }
    const int aoff = (ln15 * 4 + ((quad + (ln15 >> 1)) & 3)) * 16;
    int boff[4];
#pragma unroll
    for (int nt = 0; nt < 4; ++nt) {
        const int r = nt * 16 + ln15;
        boff[nt] = (r * 4 + ((quad + (r >> 1)) & 3)) * 16;
    }

    f4 acc[4];
#pragma unroll
    for (int j = 0; j < 4; ++j) acc[j] = (f4){0.f, 0.f, 0.f, 0.f};

    {
        f16* Al = slot;
        f16* Bl = slot + 512;
        GLLS16(Aa + ga, Al);
#pragma unroll
        for (int i = 0; i < 4; ++i) GLLS16(Bt + gb[i], Bl + i * 512);
    }
    int cur = 0;
    for (int k0 = 0; k0 < K; k0 += 32) {
        const bool more = (k0 + 32 < K);
        f16* Ac = slot + cur * 2560;
        f16* Bc = Ac + 512;
        if (more) {
            f16* An = slot + (cur ^ 1) * 2560;
            f16* Bn = An + 512;
            WAIT_LGKM0();
            GLLS16(Aa + ga + k0 + 32, An);
#pragma unroll
            for (int i = 0; i < 4; ++i) GLLS16(Bt + gb[i] + k0 + 32, Bn + i * 512);
            WAIT_VM5();
        } else {
            WAIT_VM0();
        }
        h8 aF, bF[4];
#pragma unroll
        for (int nt = 0; nt < 4; ++nt)
            bF[nt] = *(const h8*)((const char*)Bc + boff[nt]);
        aF = *(const h8*)((const char*)Ac + aoff);
#pragma unroll
        for (int nt = 0; nt < 4; ++nt)
            acc[nt] = __builtin_amdgcn_mfma_f32_16x16x32_f16(
                aF, bF[nt], acc[nt], 0, 0, 0);
        cur ^= 1;
    }

    float bsv[4], g2v[4], b2v[4];
#pragma unroll
    for (int nt = 0; nt < 4; ++nt) {
        const int gn = n0 + nt * 16 + ln15;
        bsv[nt] = bias[gn];
        g2v[nt] = g[gn];
        b2v[nt] = be[gn];
    }
    float s1[4], s2[4];
#pragma unroll
    for (int r = 0; r < 4; ++r) { s1[r] = 0.f; s2[r] = 0.f; }
#pragma unroll
    for (int r = 0; r < 4; ++r) {
        const int gm = m0 + quad * 4 + r;
#pragma unroll
        for (int nt = 0; nt < 4; ++nt) {
            const int gn = n0 + nt * 16 + ln15;
            float v = acc[nt][r] + bsv[nt] + xres[(size_t)gm * CC + gn];
            acc[nt][r] = v;
            x1[(size_t)gm * CC + gn] = (f16)v;
            s1[r] += v;
            s2[r] += v * v;
        }
    }
#pragma unroll
    for (int off = 1; off < 16; off <<= 1) {
#pragma unroll
        for (int r = 0; r < 4; ++r) {
            s1[r] += __shfl_xor(s1[r], off, 64);
            s2[r] += __shfl_xor(s2[r], off, 64);
        }
    }
    if (ln15 == 0) {
#pragma unroll
        for (int r = 0; r < 4; ++r) {
            const int rr = quad * 4 + r;
            sred[rr][wid][0] = s1[r];
            sred[rr][wid][1] = s2[r];
        }
    }
    __syncthreads();
#pragma unroll
    for (int r = 0; r < 4; ++r) {
        const int rr = quad * 4 + r;
        const int gm = m0 + rr;
        float a = 0.f, b = 0.f;
#pragma unroll
        for (int w = 0; w < 4; ++w) {
            a += sred[rr][w][0];
            b += sred[rr][w][1];
        }
        const float mu = a * (1.0f / CC);
        const float var = fmaxf(b * (1.0f / CC) - mu * mu, 0.0f);
        const float rs = rsqrtf(var + 1e-6f);
#pragma unroll
        for (int nt = 0; nt < 4; ++nt) {
            const int gn = n0 + nt * 16 + ln15;
            const float v = acc[nt][r];
            m2[(size_t)gm * CC + gn] = (f16)((v - mu) * rs * g2v[nt] + b2v[nt]);
        }
    }
}

// -------- block-coop GEMM body with counted-vmcnt pipeline (T3+T4) --------
// Exact r9 gemm_pipe body, parameterized by (m0, n0) and LDS base.
template <int BM, int BN, int WGM, int WGN, bool GELU, bool FINAL>
static __device__ __forceinline__ void pipe_body(
    const f16* __restrict__ A, const f16* __restrict__ Bt,
    const float* __restrict__ bias, const f16* __restrict__ resid16,
    void* __restrict__ outv, int N, int K, int m0, int n0, f16* lds)
{
    constexpr int A_G = BM / 16, B_G = BN / 16, T = A_G + B_G;
    constexpr int L = T / 4;                  // GLLS per wave per step
    constexpr int BUFE = (BM + BN) * 32;      // f16 elems per buffer
    constexpr int WM = BM / WGM, WN = BN / WGN;
    constexpr int MT = WM / 16;
    static_assert(WN == 64, "epilogue assumes 4 n-frags of 16");
    static_assert(T % 4 == 0, "stage loads divide across 4 waves");
    const int tid = threadIdx.x;
    const int wid = tid >> 6, lane = tid & 63;
    const int ln15 = lane & 15, quad = lane >> 4;
    const int jr = lane >> 2, js = lane & 3;
    const int wr = wid / WGN, wc = wid % WGN;

    const size_t gabase = (size_t)jr * K + (size_t)(((js - (jr >> 1)) & 3) * 8);

    int aoff[MT], boff[4];
#pragma unroll
    for (int mt = 0; mt < MT; ++mt) {
        const int rr = wr * WM + mt * 16 + ln15;
        aoff[mt] = (rr * 4 + ((quad + (rr >> 1)) & 3)) * 16;
    }
#pragma unroll
    for (int nt = 0; nt < 4; ++nt) {
        const int rr = wc * WN + nt * 16 + ln15;
        boff[nt] = BM * 64 + (rr * 4 + ((quad + (rr >> 1)) & 3)) * 16;
    }

    f4 acc[MT][4];
#pragma unroll
    for (int i = 0; i < MT; ++i)
#pragma unroll
        for (int j = 0; j < 4; ++j) acc[i][j] = (f4){0.f, 0.f, 0.f, 0.f};

#define GP_STAGE(dst, kk)                                                     \
    _Pragma("unroll")                                                         \
    for (int i = 0; i < L; ++i) {                                             \
        const int g = wid + i * 4;                                            \
        const f16* base;                                                      \
        int dofs;                                                             \
        if (g < A_G) {                                                        \
            base = A + (size_t)(m0 + g * 16) * K;                             \
            dofs = g * 512;                                                   \
        } else {                                                              \
            base = Bt + (size_t)(n0 + (g - A_G) * 16) * K;                    \
            dofs = BM * 32 + (g - A_G) * 512;                                 \
        }                                                                     \
        GLLS16(base + gabase + (kk), (dst) + dofs);                           \
    }

    // prologue: chunks 0,1 into buffers 0,1
    GP_STAGE(lds, 0);
    GP_STAGE(lds + BUFE, 32);

    const int nst = K >> 5;
    for (int s = 0; s < nst; ++s) {
        // wait until MY chunk-s loads landed; chunk-s+1's L loads stay in
        // flight across the barrier. Lingering stores from a prior job only
        // make the counted wait stricter (safe).
        if (s + 1 < nst) {
            if constexpr (L == 4) { WAIT_VM4(); } else { WAIT_VM2(); }
        } else {
            WAIT_VM0();
        }
        __builtin_amdgcn_s_barrier();          // raw: no vmcnt(0) drain
        __builtin_amdgcn_sched_barrier(0);     // pin ordering around asm waits
        if (s + 2 < nst) { GP_STAGE(lds + ((s + 2) % 3) * BUFE, (s + 2) * 32); }
        f16* bufc = lds + (s % 3) * BUFE;
        h8 aF[MT], bF[4];
#pragma unroll
        for (int nt = 0; nt < 4; ++nt)
            bF[nt] = *(const h8*)((const char*)bufc + boff[nt]);
#pragma unroll
        for (int mt = 0; mt < MT; ++mt)
            aF[mt] = *(const h8*)((const char*)bufc + aoff[mt]);
        __builtin_amdgcn_s_setprio(1);
#pragma unroll
        for (int mt = 0; mt < MT; ++mt)
#pragma unroll
            for (int nt = 0; nt < 4; ++nt)
                acc[mt][nt] = __builtin_amdgcn_mfma_f32_16x16x32_f16(
                    aF[mt], bF[nt], acc[mt][nt], 0, 0, 0);
        __builtin_amdgcn_s_setprio(0);
    }
#undef GP_STAGE

    // epilogue
#pragma unroll
    for (int nt = 0; nt < 4; ++nt) {
        const int gn = n0 + wc * WN + nt * 16 + ln15;
        const float bs = bias[gn];
#pragma unroll
        for (int mt = 0; mt < MT; ++mt) {
#pragma unroll
            for (int r = 0; r < 4; ++r) {
                const int gm = m0 + wr * WM + mt * 16 + quad * 4 + r;
                float v = acc[mt][nt][r] + bs;
                if (GELU) v = 0.5f * v * (1.0f + erff(v * 0.70710678118654752f));
                if (FINAL) {
                    v += (float)resid16[(size_t)gm * N + gn];
                    ((float*)outv)[(size_t)gm * N + gn] = v;
                } else {
                    ((f16*)outv)[(size_t)gm * N + gn] = (f16)v;
                }
            }
        }
    }
}

// ---------------- standalone kernels (non-fused fallback) ----------------
__global__ __launch_bounds__(256, 4) void gemm_op_ln2(
    const f16* __restrict__ Aa, const f16* __restrict__ Bt,
    const float* __restrict__ bias, const float* __restrict__ xres,
    const float* __restrict__ g, const float* __restrict__ be,
    f16* __restrict__ x1, f16* __restrict__ m2)
{
    __shared__ f16 lds[4 * 5120];
    __shared__ float sred[16][4][2];
    opln2_body(Aa, Bt, bias, xres, g, be, x1, m2, blockIdx.x * 16, lds, sred);
}

template <int BM, int BN, int WGM, int WGN, bool GELU, bool FINAL>
__global__ __launch_bounds__(256, 2) void gemm_pipe(
    const f16* __restrict__ A, const f16* __restrict__ Bt,
    const float* __restrict__ bias, const f16* __restrict__ resid16,
    void* __restrict__ outv, int N, int K)
{
    __shared__ f16 lds[3 * (BM + BN) * 32];
    const int sl = xcd_swizzle_lin();
    const int gx = (int)gridDim.x;
    pipe_body<BM, BN, WGM, WGN, GELU, FINAL>(
        A, Bt, bias, resid16, outv, N, K, (sl % gx) * BM, (sl / gx) * BN, lds);
}

// -------- persistent tail: op_ln2 + MLP1 + MLP2 in ONE dispatch ----------
// r10 post-mortem: hipLaunchCooperativeKernel silently failed under the
// harness (output stayed zeroed: absmax == max|ref|). Same experiment with
// a harness-safe mechanism: plain launch + software grid barrier on
// device-scope atomics. 512 blocks x 48.5 KB LDS = 2 blocks/CU (cap 3) ->
// all co-resident, barrier cannot deadlock. Counters zeroed by prep kernel
// each launch (stream-ordered). Stage bodies byte-identical to r9.
__global__ __launch_bounds__(256, 2) void tail3_kernel(
    const f16* __restrict__ ao, const f16* __restrict__ WpT,
    const float* __restrict__ bp, const float* __restrict__ x,
    const float* __restrict__ g2, const float* __restrict__ b2,
    f16* __restrict__ x1, f16* __restrict__ m2,
    const f16* __restrict__ W1T, const float* __restrict__ bm1,
    f16* __restrict__ hidF, const f16* __restrict__ W2T,
    const float* __restrict__ bm2, float* __restrict__ outp,
    unsigned* __restrict__ gctr)
{
    __shared__ f16 smem[24576];        // 48 KB: max(40 KB A, 48 KB B, 24 KB C)
    __shared__ float sred[16][4][2];
    const int bid = (int)blockIdx.x;
    const unsigned nb = gridDim.x;

    // ---- stage A: out-proj + residual + LN2 (576 x 16-row jobs) ----
    for (int j = bid; j < 576; j += (int)nb) {
        opln2_body(ao, WpT, bp, x, g2, b2, x1, m2, j * 16, smem, sred);
        __syncthreads();   // sred/smem safe for next job
    }
    sw_gbar(&gctr[0], nb);

    // ---- stage B: MLP1 gelu(m2 @ W1T + bm1) -> hidF (576 jobs, 72x8) ----
    for (int j = bid; j < 576; j += (int)nb) {
        const int sl = (j & 7) * 72 + (j >> 3);   // xcd swizzle, 576%8==0
        pipe_body<128, 128, 2, 2, true, false>(
            m2, W1T, bm1, nullptr, hidF, HID, 256,
            (sl % 72) * 128, (sl / 72) * 128, smem);
        __syncthreads();   // smem safe for next job
    }
    sw_gbar(&gctr[1], nb);

    // ---- stage C: MLP2 hidF @ W2T + bm2 + x1 -> outp (576 jobs, 144x4) ----
    for (int j = bid; j < 576; j += (int)nb) {
        const int sl = (j & 7) * 72 + (j >> 3);
        pipe_body<64, 64, 4, 1, false, true>(
            hidF, W2T, bm2, x1, outp, CC, 1024,
            (sl % 144) * 64, (sl / 144) * 64, smem);
        __syncthreads();
    }
}

// ---------------- tiled sparse spatial attention ----------------
__device__ __constant__ int ATT_DY[29] = {
    -3, -2, -2, -2, -2, -2, -1, -1, -1, -1, -1, 0, 0, 0, 0,
    0, 0, 0, 1, 1, 1, 1, 1, 2, 2, 2, 2, 2, 3};
__device__ __constant__ int ATT_DX[29] = {
    0, -2, -1, 0, 1, 2, -2, -1, 0, 1, 2, -3, -2, -1, 0,
    1, 2, 3, -2, -1, 0, 1, 2, -2, -1, 0, 1, 2, 0};

__global__ __launch_bounds__(128) void attn_tile_kernel(
    const f16* __restrict__ qf, const f16* __restrict__ kvf,
    f16* __restrict__ ao)
{
    __shared__ f16 ks[196][66];
    __shared__ f16 vs[196][66];
    const int tile = blockIdx.x, hp = blockIdx.y, b = blockIdx.z;
    const int ty0 = (tile / 6) * 8, tx0 = (tile - (tile / 6) * 6) * 8;
    const int tid = threadIdx.x;

    const int q = tid & 63, hh = tid >> 6;
    const int qy = q >> 3, qx = q & 7;
    const size_t qrow = (size_t)b * NN + (ty0 + qy) * HS + tx0 + qx;
    const f16* qp = qf + qrow * CC + hp * 64 + hh * 32;
    uint4 qa[4];
#pragma unroll
    for (int i = 0; i < 4; ++i) qa[i] = ((const uint4*)qp)[i];

#pragma unroll
    for (int bt = 0; bt < 5; ++bt) {
        uint4 v[5];
        int rr[5], sg[5];
#pragma unroll
        for (int j = 0; j < 5; ++j) {
            const int it = bt * 5 + j;
            const int idx = tid + it * 128;
            const int r = idx >> 4, seg = idx & 15;
            rr[j] = r; sg[j] = seg;
            const int ry = r / 14;
            const int gy = ty0 - 3 + ry, gx = tx0 - 3 + (r - ry * 14);
            uint4 val = {0u, 0u, 0u, 0u};
            const bool act = (it < 24) || (tid < 64);
            if (act && (unsigned)gy < HS && (unsigned)gx < HS) {
                const size_t rowb = ((size_t)b * NN + gy * HS + gx) * 512;
                const int ch = (seg < 8) ? (hp * 64 + seg * 8)
                                         : (256 + hp * 64 + (seg - 8) * 8);
                val = *(const uint4*)&kvf[rowb + ch];
            }
            v[j] = val;
        }
#pragma unroll
        for (int j = 0; j < 5; ++j) {
            const int it = bt * 5 + j;
            if (it == 24 && tid >= 64) continue;
            f16* dstp = (sg[j] < 8) ? &ks[rr[j]][(sg[j] & 7) * 8]
                                    : &vs[rr[j]][(sg[j] & 7) * 8];
            ((unsigned int*)dstp)[0] = v[j].x;
            ((unsigned int*)dstp)[1] = v[j].y;
            ((unsigned int*)dstp)[2] = v[j].z;
            ((unsigned int*)dstp)[3] = v[j].w;
        }
    }
    __syncthreads();

    const h2* q2 = (const h2*)qa;

    float s[29];
#pragma unroll
    for (int n = 0; n < 29; ++n) {
        const int dy = ATT_DY[n], dx = ATT_DX[n];
        const int r = (qy + 3 + dy) * 14 + qx + 3 + dx;
        const bool valid = (unsigned)(ty0 + qy + dy) < HS &&
                           (unsigned)(tx0 + qx + dx) < HS;
        float a = 0.0f;
        const h2* kp = (const h2*)&ks[r][hh * 32];
#pragma unroll
        for (int i = 0; i < 16; ++i)
            a = __builtin_amdgcn_fdot2(q2[i], kp[i], a, false);
        s[n] = valid ? a * ATTN_SCALE : -1e30f;
    }
    float m = s[0];
#pragma unroll
    for (int n = 1; n < 29; ++n) m = fmaxf(m, s[n]);
    float l = 0.0f;
#pragma unroll
    for (int n = 0; n < 29; ++n) { s[n] = __expf(s[n] - m); l += s[n]; }
    h2 a2[16];
#pragma unroll
    for (int i = 0; i < 16; ++i) a2[i] = (h2){(f16)0.f, (f16)0.f};
#pragma unroll
    for (int n = 0; n < 29; ++n) {
        const int dy = ATT_DY[n], dx = ATT_DX[n];
        const int r = (qy + 3 + dy) * 14 + qx + 3 + dx;
        const f16 pn = (f16)s[n];
        const h2 ph = (h2){pn, pn};
        const h2* vp = (const h2*)&vs[r][hh * 32];
#pragma unroll
        for (int i = 0; i < 16; ++i) a2[i] += ph * vp[i];
    }
    const float inv = 1.0f / l;
    uint4 ov[4];
    f16* oh = (f16*)ov;
#pragma unroll
    for (int i = 0; i < 16; ++i) {
        oh[2 * i]     = (f16)((float)a2[i][0] * inv);
        oh[2 * i + 1] = (f16)((float)a2[i][1] * inv);
    }
    uint4* dst = (uint4*)(ao + qrow * CC + hp * 64 + hh * 32);
#pragma unroll
    for (int i = 0; i < 4; ++i) dst[i] = ov[i];
}

extern "C" void kernel_launch(void* const* d_in, const int* in_sizes, int n_in,
                              void* d_out, int out_size, void* d_ws, size_t ws_size,
                              hipStream_t stream) {
    const float* x    = (const float*)d_in[0];
    const float* x_kv = (const float*)d_in[1];
    const float* Wq   = (const float*)d_in[2];
    const float* bq   = (const float*)d_in[3];
    const float* Wk   = (const float*)d_in[4];
    const float* bk   = (const float*)d_in[5];
    const float* Wv   = (const float*)d_in[6];
    const float* bv   = (const float*)d_in[7];
    const float* Wp   = (const float*)d_in[8];
    const float* bp   = (const float*)d_in[9];
    const float* g1   = (const float*)d_in[10];
    const float* b1   = (const float*)d_in[11];
    const float* g2   = (const float*)d_in[12];
    const float* b2   = (const float*)d_in[13];
    const float* W1   = (const float*)d_in[14];
    const float* bm1  = (const float*)d_in[15];
    const float* W2   = (const float*)d_in[16];
    const float* bm2  = (const float*)d_in[17];
    float* outp = (float*)d_out;   // fp32 output (verified)

    // ws layout (f16 element offsets); overlays by stream-ordered lifetime:
    //   ao over hq (dead after qkv); x1 over hkv (dead after qkv);
    //   m2 over qf (dead after attn); hidF over kvf.. (dead after attn).
    f16* wsh = (f16*)d_ws;
    f16* WqkvT = wsh;                      // 196608
    f16* WpT   = wsh + 196608;             // 65536
    f16* W1T   = wsh + 262144;             // 262144
    f16* W2T   = wsh + 524288;             // 262144
    float* bqkv = (float*)(wsh + 786432);  // 768 fp32
    f16* hq    = wsh + 787968;             // 2359296
    f16* hkv   = wsh + 3147264;            // 2359296
    f16* qf    = wsh + 5506560;            // 2359296
    f16* kvf   = wsh + 7865856;            // 4718592 (end 12584448)
    f16* ao    = hq;
    f16* x1    = hkv;
    f16* m2    = qf;
    f16* hidF  = kvf;                      // 9437184 -> end 17303040 (34.6 MB)
    unsigned* gctr = (unsigned*)(wsh + 17303040);   // 8 x u32 barrier ctrs
    const bool fused = ws_size >= (size_t)17303040 * sizeof(f16) + 256;

    // 1. merged weight prep + LN1 (769 + 4608 blocks); zeroes barrier ctrs
    prep_ln1_kernel<<<5377, 256, 0, stream>>>(
        x, x_kv, Wq, Wk, Wv, Wp, W1, W2, bq, bk, bv, g1, b1,
        WqkvT, WpT, W1T, W2T, bqkv, hq, hkv, fused ? gctr : nullptr);
    // 2. fused Q|K|V projection: tiles 288(M) x 12(N), double-buffered (r5)
    gemm_wave<true><<<dim3(12, 72), 256, 0, stream>>>(
        hq, hkv, WqkvT, bqkv, qf, kvf, 768, 256);
    // 3. attention
    attn_tile_kernel<<<dim3(36, 4, BB), 128, 0, stream>>>(qf, kvf, ao);
    // 4. persistent tail: op_ln2 + MLP1 + MLP2, one dispatch, sw barriers
    if (fused) {
        tail3_kernel<<<512, 256, 0, stream>>>(
            ao, WpT, bp, x, g2, b2, x1, m2,
            W1T, bm1, hidF, W2T, bm2, outp, gctr);
    } else {
        gemm_op_ln2<<<576, 256, 0, stream>>>(ao, WpT, bp, x, g2, b2, x1, m2);
        for (int b = 0; b < BB; ++b) {
            const size_t off = (size_t)b * NN * CC;
            gemm_pipe<128, 128, 2, 2, true, false>
                <<<dim3(18, 8), 256, 0, stream>>>(
                    m2 + off, W1T, bm1, nullptr, hidF, HID, 256);
            gemm_pipe<64, 64, 4, 1, false, true>
                <<<dim3(36, 4), 256, 0, stream>>>(
                    hidF, W2T, bm2, x1 + off, outp + off, CC, 1024);
        }
    }
    (void)in_sizes; (void)n_in; (void)out_size;
}

// Round 12
// 176.694 us; speedup vs baseline: 2.8691x; 2.8691x over previous
//
#include <hip/hip_runtime.h>
#include <hip/hip_fp16.h>
#include <math.h>

#define BB 4
#define NN 2304
#define CC 256
#define HS 48
#define HID 1024
#define BNROWS (BB * NN)                 // 9216
#define ATTN_SCALE 0.17677669529663687f  // 32^-0.5

typedef _Float16 f16;
typedef __attribute__((ext_vector_type(2))) _Float16 h2;
typedef __attribute__((ext_vector_type(8))) _Float16 h8;
typedef __attribute__((ext_vector_type(4))) float f4;

#define GLLS16(g, l)                                                        \
    __builtin_amdgcn_global_load_lds(                                       \
        (const __attribute__((address_space(1))) unsigned int*)(g),         \
        (__attribute__((address_space(3))) unsigned int*)(l), 16, 0, 0)
// global_load_lds -> ds_read dependency is untracked by the compiler;
// explicit waits with memory clobber pin the ordering.
#define WAIT_VM0()   asm volatile("s_waitcnt vmcnt(0)" ::: "memory")
#define WAIT_VM2()   asm volatile("s_waitcnt vmcnt(2)" ::: "memory")
#define WAIT_VM4()   asm volatile("s_waitcnt vmcnt(4)" ::: "memory")
#define WAIT_VM5()   asm volatile("s_waitcnt vmcnt(5)" ::: "memory")
#define WAIT_VM6()   asm volatile("s_waitcnt vmcnt(6)" ::: "memory")
#define WAIT_LGKM0() asm volatile("s_waitcnt lgkmcnt(0)" ::: "memory")

static __device__ __forceinline__ float wave_sum64(float v) {
    v += __shfl_xor(v, 32, 64);
    v += __shfl_xor(v, 16, 64);
    v += __shfl_xor(v, 8, 64);
    v += __shfl_xor(v, 4, 64);
    v += __shfl_xor(v, 2, 64);
    v += __shfl_xor(v, 1, 64);
    return v;
}

// bijective XCD swizzle: cluster consecutive linear block ids onto one XCD so
// blocks sharing a B-panel hit the same per-XCD L2. Requires nwg % 8 == 0.
static __device__ __forceinline__ int xcd_swizzle_lin() {
    const int gx = (int)gridDim.x;
    const int lin = (int)blockIdx.y * gx + (int)blockIdx.x;
    const int nwg = gx * (int)gridDim.y;
    return (nwg & 7) ? lin : ((lin & 7) * (nwg >> 3) + (lin >> 3));
}

// ---------------- merged prep + LN1 ----------------
__global__ __launch_bounds__(256) void prep_ln1_kernel(
    const float* __restrict__ x, const float* __restrict__ xkv,
    const float* __restrict__ Wq, const float* __restrict__ Wk,
    const float* __restrict__ Wv, const float* __restrict__ Wp,
    const float* __restrict__ W1, const float* __restrict__ W2,
    const float* __restrict__ bq, const float* __restrict__ bk,
    const float* __restrict__ bv,
    const float* __restrict__ g, const float* __restrict__ be,
    f16* __restrict__ WqkvT, f16* __restrict__ WpT,
    f16* __restrict__ W1T, f16* __restrict__ W2T, float* __restrict__ bqkv,
    f16* __restrict__ hq, f16* __restrict__ hkv)
{
    __shared__ float tt[32][33];
    int bx = blockIdx.x;
    const int tid = threadIdx.x;
    if (bx < 768) {
        const float* src; f16* dst; int K, N;
        if (bx < 64)        { src = Wq; dst = WqkvT;           K = 256;  N = 256; }
        else if (bx < 128)  { src = Wk; dst = WqkvT + 65536;   K = 256;  N = 256;  bx -= 64; }
        else if (bx < 192)  { src = Wv; dst = WqkvT + 131072;  K = 256;  N = 256;  bx -= 128; }
        else if (bx < 256)  { src = Wp; dst = WpT;             K = 256;  N = 256;  bx -= 192; }
        else if (bx < 512)  { src = W1; dst = W1T;             K = 256;  N = 1024; bx -= 256; }
        else                { src = W2; dst = W2T;             K = 1024; N = 256;  bx -= 512; }
        const int tN = N >> 5;
        const int kt = bx / tN, nt = bx - kt * tN;
        const int rr = tid >> 5, cc = tid & 31;
#pragma unroll
        for (int j = 0; j < 4; ++j)
            tt[rr + 8 * j][cc] = src[(size_t)(kt * 32 + rr + 8 * j) * N + nt * 32 + cc];
        __syncthreads();
#pragma unroll
        for (int j = 0; j < 4; ++j)
            dst[(size_t)(nt * 32 + rr + 8 * j) * K + kt * 32 + cc] = (f16)tt[cc][rr + 8 * j];
        return;
    }
    if (bx == 768) {
        if (tid < 256) {
            bqkv[tid]       = bq[tid];
            bqkv[tid + 256] = bk[tid];
            bqkv[tid + 512] = bv[tid];
        }
        return;
    }
    // LN1
    const int r = (bx - 769) * 4 + (tid >> 6);  // 0..2*BNROWS-1
    const int lane = tid & 63;
    const float* src; f16* dst;
    if (r < BNROWS) { src = x + (size_t)r * CC;              dst = hq + (size_t)r * CC; }
    else { src = xkv + (size_t)(r - BNROWS) * CC; dst = hkv + (size_t)(r - BNROWS) * CC; }
    const float4 v = ((const float4*)src)[lane];
    const float mu = wave_sum64(v.x + v.y + v.z + v.w) * (1.0f / CC);
    const float d0 = v.x - mu, d1 = v.y - mu, d2 = v.z - mu, d3 = v.w - mu;
    const float var = wave_sum64(d0 * d0 + d1 * d1 + d2 * d2 + d3 * d3) * (1.0f / CC);
    const float rs = rsqrtf(var + 1e-6f);
    const float4 g4 = ((const float4*)g)[lane];
    const float4 b4 = ((const float4*)be)[lane];
    h2 o01 = (h2){(f16)(d0 * rs * g4.x + b4.x), (f16)(d1 * rs * g4.y + b4.y)};
    h2 o23 = (h2){(f16)(d2 * rs * g4.z + b4.z), (f16)(d3 * rs * g4.w + b4.w)};
    ((h2*)dst)[lane * 2] = o01;
    ((h2*)dst)[lane * 2 + 1] = o23;
}

// ---------------- wave-autonomous MFMA GEMM, double-buffered (QKV) --------
// Exact r5 structure (best measured). Wave owns 32(M)x64(N); two private
// 6 KB buffers; vmcnt(6) drains only the 6 oldest loads.
template <bool QKV>
__global__ __launch_bounds__(256, 4) void gemm_wave(
    const f16* __restrict__ Aq, const f16* __restrict__ Akv,
    const f16* __restrict__ Bt, const float* __restrict__ bias,
    void* __restrict__ out1, void* __restrict__ outkv, int N, int K)
{
    __shared__ f16 lds[4 * 6144];   // 4 waves x 2 buffers x 3072 f16 = 48 KB
    const int tid = threadIdx.x;
    const int wid = tid >> 6, lane = tid & 63;
    const int ln15 = lane & 15, quad = lane >> 4;
    const int jr = lane >> 2, js = lane & 3;
    f16* slot = lds + wid * 6144;
    const int sl = xcd_swizzle_lin();
    const int gx = (int)gridDim.x;
    const int bx = sl % gx, by = sl / gx;
    const int n0 = bx * 64;
    const int m0 = (by * 4 + wid) * 32;
    const f16* Ap = QKV ? (n0 < 256 ? Aq : Akv) : Aq;

    size_t ga[2], gb[4];
#pragma unroll
    for (int i = 0; i < 2; ++i) {
        const int r = i * 16 + jr;
        const int q = (js - (r >> 1)) & 3;
        ga[i] = (size_t)(m0 + r) * K + q * 8;
    }
#pragma unroll
    for (int i = 0; i < 4; ++i) {
        const int r = i * 16 + jr;
        const int q = (js - (r >> 1)) & 3;
        gb[i] = (size_t)(n0 + r) * K + q * 8;
    }
    int aoff[2], boff[4];
#pragma unroll
    for (int mt = 0; mt < 2; ++mt) {
        const int r = mt * 16 + ln15;
        aoff[mt] = (r * 4 + ((quad + (r >> 1)) & 3)) * 16;
    }
#pragma unroll
    for (int nt = 0; nt < 4; ++nt) {
        const int r = nt * 16 + ln15;
        boff[nt] = (r * 4 + ((quad + (r >> 1)) & 3)) * 16;
    }

    f4 acc[2][4];
#pragma unroll
    for (int i = 0; i < 2; ++i)
#pragma unroll
        for (int j = 0; j < 4; ++j) acc[i][j] = (f4){0.f, 0.f, 0.f, 0.f};

    {
        f16* Al = slot;
        f16* Bl = slot + 1024;
#pragma unroll
        for (int i = 0; i < 2; ++i) GLLS16(Ap + ga[i], Al + i * 512);
#pragma unroll
        for (int i = 0; i < 4; ++i) GLLS16(Bt + gb[i], Bl + i * 512);
    }

    int cur = 0;
    for (int k0 = 0; k0 < K; k0 += 32) {
        const bool more = (k0 + 32 < K);
        f16* Ac = slot + cur * 3072;
        f16* Bc = Ac + 1024;
        if (more) {
            f16* An = slot + (cur ^ 1) * 3072;
            f16* Bn = An + 1024;
            WAIT_LGKM0();
#pragma unroll
            for (int i = 0; i < 2; ++i) GLLS16(Ap + ga[i] + k0 + 32, An + i * 512);
#pragma unroll
            for (int i = 0; i < 4; ++i) GLLS16(Bt + gb[i] + k0 + 32, Bn + i * 512);
            WAIT_VM6();
        } else {
            WAIT_VM0();
        }
        h8 aF[2], bF[4];
#pragma unroll
        for (int nt = 0; nt < 4; ++nt)
            bF[nt] = *(const h8*)((const char*)Bc + boff[nt]);
#pragma unroll
        for (int mt = 0; mt < 2; ++mt)
            aF[mt] = *(const h8*)((const char*)Ac + aoff[mt]);
#pragma unroll
        for (int mt = 0; mt < 2; ++mt)
#pragma unroll
            for (int nt = 0; nt < 4; ++nt)
                acc[mt][nt] = __builtin_amdgcn_mfma_f32_16x16x32_f16(
                    aF[mt], bF[nt], acc[mt][nt], 0, 0, 0);
        cur ^= 1;
    }

    // epilogue; for QKV the 64-col block never straddles the Q|KV split.
    f16* qdst = nullptr; int qstr = 0, qn0 = 0;
    if (QKV) {
        if (n0 < 256) { qdst = (f16*)out1;  qstr = 256; qn0 = n0; }
        else          { qdst = (f16*)outkv; qstr = 512; qn0 = n0 - 256; }
    }
#pragma unroll
    for (int nt = 0; nt < 4; ++nt) {
        const int gn = n0 + nt * 16 + ln15;
        const float bs = bias[gn];
#pragma unroll
        for (int mt = 0; mt < 2; ++mt) {
#pragma unroll
            for (int r = 0; r < 4; ++r) {
                const int gm = m0 + mt * 16 + quad * 4 + r;
                float v = acc[mt][nt][r] + bs;
                if (QKV) {
                    qdst[(size_t)gm * qstr + qn0 + nt * 16 + ln15] = (f16)v;
                } else {
                    ((f16*)out1)[(size_t)gm * N + gn] = (f16)v;
                }
            }
        }
    }
}

// ---------------- fused out-proj + residual + LN2 (16-row blocks) ----------
// Block owns 16 complete rows; 4 waves are the 4 N-tiles (n0 = wid*64).
__global__ __launch_bounds__(256, 4) void gemm_op_ln2(
    const f16* __restrict__ Aa, const f16* __restrict__ Bt,
    const float* __restrict__ bias, const float* __restrict__ xres,
    const float* __restrict__ g, const float* __restrict__ be,
    f16* __restrict__ x1, f16* __restrict__ m2)
{
    __shared__ f16 lds[4 * 5120];       // 4 waves x 2 buf x (512 A + 2048 B)
    __shared__ float sred[16][4][2];
    const int tid = threadIdx.x;
    const int wid = tid >> 6, lane = tid & 63;
    const int ln15 = lane & 15, quad = lane >> 4;
    const int jr = lane >> 2, js = lane & 3;
    f16* slot = lds + wid * 5120;
    const int m0 = blockIdx.x * 16;
    const int n0 = wid * 64;
    const int K = 256;

    size_t ga, gb[4];
    {
        const int q = (js - (jr >> 1)) & 3;
        ga = (size_t)(m0 + jr) * K + q * 8;
    }
#pragma unroll
    for (int i = 0; i < 4; ++i) {
        const int r = i * 16 + jr;
        const int q = (js - (r >> 1)) & 3;
        gb[i] = (size_t)(n0 + r) * K + q * 8;
    }
    const int aoff = (ln15 * 4 + ((quad + (ln15 >> 1)) & 3)) * 16;
    int boff[4];
#pragma unroll
    for (int nt = 0; nt < 4; ++nt) {
        const int r = nt * 16 + ln15;
        boff[nt] = (r * 4 + ((quad + (r >> 1)) & 3)) * 16;
    }

    f4 acc[4];
#pragma unroll
    for (int j = 0; j < 4; ++j) acc[j] = (f4){0.f, 0.f, 0.f, 0.f};

    {
        f16* Al = slot;
        f16* Bl = slot + 512;
        GLLS16(Aa + ga, Al);
#pragma unroll
        for (int i = 0; i < 4; ++i) GLLS16(Bt + gb[i], Bl + i * 512);
    }
    int cur = 0;
    for (int k0 = 0; k0 < K; k0 += 32) {
        const bool more = (k0 + 32 < K);
        f16* Ac = slot + cur * 2560;
        f16* Bc = Ac + 512;
        if (more) {
            f16* An = slot + (cur ^ 1) * 2560;
            f16* Bn = An + 512;
            WAIT_LGKM0();
            GLLS16(Aa + ga + k0 + 32, An);
#pragma unroll
            for (int i = 0; i < 4; ++i) GLLS16(Bt + gb[i] + k0 + 32, Bn + i * 512);
            WAIT_VM5();
        } else {
            WAIT_VM0();
        }
        h8 aF, bF[4];
#pragma unroll
        for (int nt = 0; nt < 4; ++nt)
            bF[nt] = *(const h8*)((const char*)Bc + boff[nt]);
        aF = *(const h8*)((const char*)Ac + aoff);
#pragma unroll
        for (int nt = 0; nt < 4; ++nt)
            acc[nt] = __builtin_amdgcn_mfma_f32_16x16x32_f16(
                aF, bF[nt], acc[nt], 0, 0, 0);
        cur ^= 1;
    }

    float bsv[4], g2v[4], b2v[4];
#pragma unroll
    for (int nt = 0; nt < 4; ++nt) {
        const int gn = n0 + nt * 16 + ln15;
        bsv[nt] = bias[gn];
        g2v[nt] = g[gn];
        b2v[nt] = be[gn];
    }
    float s1[4], s2[4];
#pragma unroll
    for (int r = 0; r < 4; ++r) { s1[r] = 0.f; s2[r] = 0.f; }
#pragma unroll
    for (int r = 0; r < 4; ++r) {
        const int gm = m0 + quad * 4 + r;
#pragma unroll
        for (int nt = 0; nt < 4; ++nt) {
            const int gn = n0 + nt * 16 + ln15;
            float v = acc[nt][r] + bsv[nt] + xres[(size_t)gm * CC + gn];
            acc[nt][r] = v;
            x1[(size_t)gm * CC + gn] = (f16)v;
            s1[r] += v;
            s2[r] += v * v;
        }
    }
#pragma unroll
    for (int off = 1; off < 16; off <<= 1) {
#pragma unroll
        for (int r = 0; r < 4; ++r) {
            s1[r] += __shfl_xor(s1[r], off, 64);
            s2[r] += __shfl_xor(s2[r], off, 64);
        }
    }
    if (ln15 == 0) {
#pragma unroll
        for (int r = 0; r < 4; ++r) {
            const int rr = quad * 4 + r;
            sred[rr][wid][0] = s1[r];
            sred[rr][wid][1] = s2[r];
        }
    }
    __syncthreads();
#pragma unroll
    for (int r = 0; r < 4; ++r) {
        const int rr = quad * 4 + r;
        const int gm = m0 + rr;
        float a = 0.f, b = 0.f;
#pragma unroll
        for (int w = 0; w < 4; ++w) {
            a += sred[rr][w][0];
            b += sred[rr][w][1];
        }
        const float mu = a * (1.0f / CC);
        const float var = fmaxf(b * (1.0f / CC) - mu * mu, 0.0f);
        const float rs = rsqrtf(var + 1e-6f);
#pragma unroll
        for (int nt = 0; nt < 4; ++nt) {
            const int gn = n0 + nt * 16 + ln15;
            const float v = acc[nt][r];
            m2[(size_t)gm * CC + gn] = (f16)((v - mu) * rs * g2v[nt] + b2v[nt]);
        }
    }
}

// -------- block-coop GEMM with counted-vmcnt pipeline (T3+T4, MLP) --------
// 3 LDS buffers, prefetch depth 2, RAW s_barrier and a counted vmcnt(L):
// at step s we wait only until step-s loads landed (step-s+1's L loads stay
// in flight across the barrier). WAR-safe: stage into buf[(s+2)%3] is issued
// AFTER the barrier, by which point every wave finished reading that buffer.
// T5 setprio wraps the MFMA cluster. Ascending-k accumulation.
template <int BM, int BN, int WGM, int WGN, bool GELU, bool FINAL>
__global__ __launch_bounds__(256, 2) void gemm_pipe(
    const f16* __restrict__ A, const f16* __restrict__ Bt,
    const float* __restrict__ bias, const f16* __restrict__ resid16,
    void* __restrict__ outv, int N, int K)
{
    constexpr int A_G = BM / 16, B_G = BN / 16, T = A_G + B_G;
    constexpr int L = T / 4;                  // GLLS per wave per step
    constexpr int BUFE = (BM + BN) * 32;      // f16 elems per buffer
    constexpr int WM = BM / WGM, WN = BN / WGN;
    constexpr int MT = WM / 16;
    static_assert(WN == 64, "epilogue assumes 4 n-frags of 16");
    static_assert(T % 4 == 0, "stage loads divide across 4 waves");
    __shared__ f16 lds[3 * BUFE];
    const int tid = threadIdx.x;
    const int wid = tid >> 6, lane = tid & 63;
    const int ln15 = lane & 15, quad = lane >> 4;
    const int jr = lane >> 2, js = lane & 3;
    const int wr = wid / WGN, wc = wid % WGN;

    const int sl = xcd_swizzle_lin();
    const int gx = (int)gridDim.x;
    const int m0 = (sl % gx) * BM;
    const int n0 = (sl / gx) * BN;

    const size_t gabase = (size_t)jr * K + (size_t)(((js - (jr >> 1)) & 3) * 8);

    int aoff[MT], boff[4];
#pragma unroll
    for (int mt = 0; mt < MT; ++mt) {
        const int rr = wr * WM + mt * 16 + ln15;
        aoff[mt] = (rr * 4 + ((quad + (rr >> 1)) & 3)) * 16;
    }
#pragma unroll
    for (int nt = 0; nt < 4; ++nt) {
        const int rr = wc * WN + nt * 16 + ln15;
        boff[nt] = BM * 64 + (rr * 4 + ((quad + (rr >> 1)) & 3)) * 16;
    }

    f4 acc[MT][4];
#pragma unroll
    for (int i = 0; i < MT; ++i)
#pragma unroll
        for (int j = 0; j < 4; ++j) acc[i][j] = (f4){0.f, 0.f, 0.f, 0.f};

#define GP_STAGE(dst, kk)                                                     \
    _Pragma("unroll")                                                         \
    for (int i = 0; i < L; ++i) {                                             \
        const int g = wid + i * 4;                                            \
        const f16* base;                                                      \
        int dofs;                                                             \
        if (g < A_G) {                                                        \
            base = A + (size_t)(m0 + g * 16) * K;                             \
            dofs = g * 512;                                                   \
        } else {                                                              \
            base = Bt + (size_t)(n0 + (g - A_G) * 16) * K;                    \
            dofs = BM * 32 + (g - A_G) * 512;                                 \
        }                                                                     \
        GLLS16(base + gabase + (kk), (dst) + dofs);                           \
    }

    // prologue: chunks 0,1 into buffers 0,1
    GP_STAGE(lds, 0);
    GP_STAGE(lds + BUFE, 32);

    const int nst = K >> 5;
    for (int s = 0; s < nst; ++s) {
        // wait until MY chunk-s loads landed; chunk-s+1's L loads stay in
        // flight across the barrier (the whole point).
        if (s + 1 < nst) {
            if constexpr (L == 4) { WAIT_VM4(); } else { WAIT_VM2(); }
        } else {
            WAIT_VM0();
        }
        __builtin_amdgcn_s_barrier();          // raw: no vmcnt(0) drain
        __builtin_amdgcn_sched_barrier(0);     // pin ordering around asm waits
        if (s + 2 < nst) { GP_STAGE(lds + ((s + 2) % 3) * BUFE, (s + 2) * 32); }
        f16* bufc = lds + (s % 3) * BUFE;
        h8 aF[MT], bF[4];
#pragma unroll
        for (int nt = 0; nt < 4; ++nt)
            bF[nt] = *(const h8*)((const char*)bufc + boff[nt]);
#pragma unroll
        for (int mt = 0; mt < MT; ++mt)
            aF[mt] = *(const h8*)((const char*)bufc + aoff[mt]);
        __builtin_amdgcn_s_setprio(1);
#pragma unroll
        for (int mt = 0; mt < MT; ++mt)
#pragma unroll
            for (int nt = 0; nt < 4; ++nt)
                acc[mt][nt] = __builtin_amdgcn_mfma_f32_16x16x32_f16(
                    aF[mt], bF[nt], acc[mt][nt], 0, 0, 0);
        __builtin_amdgcn_s_setprio(0);
    }
#undef GP_STAGE

    // epilogue
#pragma unroll
    for (int nt = 0; nt < 4; ++nt) {
        const int gn = n0 + wc * WN + nt * 16 + ln15;
        const float bs = bias[gn];
#pragma unroll
        for (int mt = 0; mt < MT; ++mt) {
#pragma unroll
            for (int r = 0; r < 4; ++r) {
                const int gm = m0 + wr * WM + mt * 16 + quad * 4 + r;
                float v = acc[mt][nt][r] + bs;
                if (GELU) v = 0.5f * v * (1.0f + erff(v * 0.70710678118654752f));
                if (FINAL) {
                    v += (float)resid16[(size_t)gm * N + gn];
                    ((float*)outv)[(size_t)gm * N + gn] = v;
                } else {
                    ((f16*)outv)[(size_t)gm * N + gn] = (f16)v;
                }
            }
        }
    }
}

// ---------------- tiled sparse spatial attention ----------------
__device__ __constant__ int ATT_DY[29] = {
    -3, -2, -2, -2, -2, -2, -1, -1, -1, -1, -1, 0, 0, 0, 0,
    0, 0, 0, 1, 1, 1, 1, 1, 2, 2, 2, 2, 2, 3};
__device__ __constant__ int ATT_DX[29] = {
    0, -2, -1, 0, 1, 2, -2, -1, 0, 1, 2, -3, -2, -1, 0,
    1, 2, 3, -2, -1, 0, 1, 2, -2, -1, 0, 1, 2, 0};

__global__ __launch_bounds__(128) void attn_tile_kernel(
    const f16* __restrict__ qf, const f16* __restrict__ kvf,
    f16* __restrict__ ao)
{
    __shared__ f16 ks[196][66];
    __shared__ f16 vs[196][66];
    const int tile = blockIdx.x, hp = blockIdx.y, b = blockIdx.z;
    const int ty0 = (tile / 6) * 8, tx0 = (tile - (tile / 6) * 6) * 8;
    const int tid = threadIdx.x;

    const int q = tid & 63, hh = tid >> 6;
    const int qy = q >> 3, qx = q & 7;
    const size_t qrow = (size_t)b * NN + (ty0 + qy) * HS + tx0 + qx;
    const f16* qp = qf + qrow * CC + hp * 64 + hh * 32;
    uint4 qa[4];
#pragma unroll
    for (int i = 0; i < 4; ++i) qa[i] = ((const uint4*)qp)[i];

#pragma unroll
    for (int bt = 0; bt < 5; ++bt) {
        uint4 v[5];
        int rr[5], sg[5];
#pragma unroll
        for (int j = 0; j < 5; ++j) {
            const int it = bt * 5 + j;
            const int idx = tid + it * 128;
            const int r = idx >> 4, seg = idx & 15;
            rr[j] = r; sg[j] = seg;
            const int ry = r / 14;
            const int gy = ty0 - 3 + ry, gx = tx0 - 3 + (r - ry * 14);
            uint4 val = {0u, 0u, 0u, 0u};
            const bool act = (it < 24) || (tid < 64);
            if (act && (unsigned)gy < HS && (unsigned)gx < HS) {
                const size_t rowb = ((size_t)b * NN + gy * HS + gx) * 512;
                const int ch = (seg < 8) ? (hp * 64 + seg * 8)
                                         : (256 + hp * 64 + (seg - 8) * 8);
                val = *(const uint4*)&kvf[rowb + ch];
            }
            v[j] = val;
        }
#pragma unroll
        for (int j = 0; j < 5; ++j) {
            const int it = bt * 5 + j;
            if (it == 24 && tid >= 64) continue;
            f16* dstp = (sg[j] < 8) ? &ks[rr[j]][(sg[j] & 7) * 8]
                                    : &vs[rr[j]][(sg[j] & 7) * 8];
            ((unsigned int*)dstp)[0] = v[j].x;
            ((unsigned int*)dstp)[1] = v[j].y;
            ((unsigned int*)dstp)[2] = v[j].z;
            ((unsigned int*)dstp)[3] = v[j].w;
        }
    }
    __syncthreads();

    const h2* q2 = (const h2*)qa;

    float s[29];
#pragma unroll
    for (int n = 0; n < 29; ++n) {
        const int dy = ATT_DY[n], dx = ATT_DX[n];
        const int r = (qy + 3 + dy) * 14 + qx + 3 + dx;
        const bool valid = (unsigned)(ty0 + qy + dy) < HS &&
                           (unsigned)(tx0 + qx + dx) < HS;
        float a = 0.0f;
        const h2* kp = (const h2*)&ks[r][hh * 32];
#pragma unroll
        for (int i = 0; i < 16; ++i)
            a = __builtin_amdgcn_fdot2(q2[i], kp[i], a, false);
        s[n] = valid ? a * ATTN_SCALE : -1e30f;
    }
    float m = s[0];
#pragma unroll
    for (int n = 1; n < 29; ++n) m = fmaxf(m, s[n]);
    float l = 0.0f;
#pragma unroll
    for (int n = 0; n < 29; ++n) { s[n] = __expf(s[n] - m); l += s[n]; }
    h2 a2[16];
#pragma unroll
    for (int i = 0; i < 16; ++i) a2[i] = (h2){(f16)0.f, (f16)0.f};
#pragma unroll
    for (int n = 0; n < 29; ++n) {
        const int dy = ATT_DY[n], dx = ATT_DX[n];
        const int r = (qy + 3 + dy) * 14 + qx + 3 + dx;
        const f16 pn = (f16)s[n];
        const h2 ph = (h2){pn, pn};
        const h2* vp = (const h2*)&vs[r][hh * 32];
#pragma unroll
        for (int i = 0; i < 16; ++i) a2[i] += ph * vp[i];
    }
    const float inv = 1.0f / l;
    uint4 ov[4];
    f16* oh = (f16*)ov;
#pragma unroll
    for (int i = 0; i < 16; ++i) {
        oh[2 * i]     = (f16)((float)a2[i][0] * inv);
        oh[2 * i + 1] = (f16)((float)a2[i][1] * inv);
    }
    uint4* dst = (uint4*)(ao + qrow * CC + hp * 64 + hh * 32);
#pragma unroll
    for (int i = 0; i < 4; ++i) dst[i] = ov[i];
}

extern "C" void kernel_launch(void* const* d_in, const int* in_sizes, int n_in,
                              void* d_out, int out_size, void* d_ws, size_t ws_size,
                              hipStream_t stream) {
    const float* x    = (const float*)d_in[0];
    const float* x_kv = (const float*)d_in[1];
    const float* Wq   = (const float*)d_in[2];
    const float* bq   = (const float*)d_in[3];
    const float* Wk   = (const float*)d_in[4];
    const float* bk   = (const float*)d_in[5];
    const float* Wv   = (const float*)d_in[6];
    const float* bv   = (const float*)d_in[7];
    const float* Wp   = (const float*)d_in[8];
    const float* bp   = (const float*)d_in[9];
    const float* g1   = (const float*)d_in[10];
    const float* b1   = (const float*)d_in[11];
    const float* g2   = (const float*)d_in[12];
    const float* b2   = (const float*)d_in[13];
    const float* W1   = (const float*)d_in[14];
    const float* bm1  = (const float*)d_in[15];
    const float* W2   = (const float*)d_in[16];
    const float* bm2  = (const float*)d_in[17];
    float* outp = (float*)d_out;   // fp32 output (verified)

    // ws layout (f16 element offsets); overlays by stream-ordered lifetime:
    //   ao over hq (dead after qkv); x1 over hkv (dead after qkv);
    //   m2 over qf (dead after attn); hidF over kvf.. (dead after attn).
    f16* wsh = (f16*)d_ws;
    f16* WqkvT = wsh;                      // 196608
    f16* WpT   = wsh + 196608;             // 65536
    f16* W1T   = wsh + 262144;             // 262144
    f16* W2T   = wsh + 524288;             // 262144
    float* bqkv = (float*)(wsh + 786432);  // 768 fp32
    f16* hq    = wsh + 787968;             // 2359296
    f16* hkv   = wsh + 3147264;            // 2359296
    f16* qf    = wsh + 5506560;            // 2359296
    f16* kvf   = wsh + 7865856;            // 4718592 (end 12584448)
    f16* ao    = hq;
    f16* x1    = hkv;
    f16* m2    = qf;
    f16* hidF  = kvf;                      // 9437184 -> end 17303040 (34.6 MB)
    const bool fused = ws_size >= (size_t)17303040 * sizeof(f16);

    // 1. merged weight prep + LN1 (769 + 4608 blocks)
    prep_ln1_kernel<<<5377, 256, 0, stream>>>(
        x, x_kv, Wq, Wk, Wv, Wp, W1, W2, bq, bk, bv, g1, b1,
        WqkvT, WpT, W1T, W2T, bqkv, hq, hkv);
    // 2. fused Q|K|V projection: tiles 288(M) x 12(N), double-buffered (r5)
    gemm_wave<true><<<dim3(12, 72), 256, 0, stream>>>(
        hq, hkv, WqkvT, bqkv, qf, kvf, 768, 256);
    // 3. attention
    attn_tile_kernel<<<dim3(36, 4, BB), 128, 0, stream>>>(qf, kvf, ao);
    // 4. out-proj + fp32 x residual -> x1 (f16), fused LN2 -> m2 (f16)
    gemm_op_ln2<<<576, 256, 0, stream>>>(ao, WpT, bp, x, g2, b2, x1, m2);
    // 5/6. MLP: counted-vmcnt pipelined block-coop GEMMs (raw s_barrier,
    // prefetch depth 2 across barriers).
    if (fused) {
        gemm_pipe<128, 128, 2, 2, true, false>
            <<<dim3(72, 8), 256, 0, stream>>>(
                m2, W1T, bm1, nullptr, hidF, HID, 256);
        gemm_pipe<64, 64, 4, 1, false, true>
            <<<dim3(144, 4), 256, 0, stream>>>(
                hidF, W2T, bm2, x1, outp, CC, 1024);
    } else {
        for (int b = 0; b < BB; ++b) {
            const size_t off = (size_t)b * NN * CC;
            gemm_pipe<128, 128, 2, 2, true, false>
                <<<dim3(18, 8), 256, 0, stream>>>(
                    m2 + off, W1T, bm1, nullptr, hidF, HID, 256);
            gemm_pipe<64, 64, 4, 1, false, true>
                <<<dim3(36, 4), 256, 0, stream>>>(
                    hidF, W2T, bm2, x1 + off, outp + off, CC, 1024);
        }
    }
    (void)in_sizes; (void)n_in; (void)out_size;
}